// Round 1
// 192.776 us; speedup vs baseline: 1.0096x; 1.0096x over previous
//
#include <hip/hip_runtime.h>

// Inputs: [32,3,512,512] f32; pooled grid 128x128 per image.
#define HH 512
#define WW 512
#define PH 128
#define PW 128
#define CC 3

typedef float f32x4 __attribute__((ext_vector_type(4)));

// Kernel 1: g[b,i,j] = (1/48) * sum_{c, 4x4 block} (orig - enh)
//
// R6: occupancy-first restructure. Flat grid (2048 blocks, 1 cell/thread,
// no grid-stride) + per-channel load-8/accumulate so peak live staging is
// 8 f32x4 (32 VGPR) instead of 24 (96 VGPR). __launch_bounds__(256,8)
// forces VGPR<=64 -> 8 waves/SIMD = 32 waves/CU (vs 2 waves/SIMD before).
// Theory: pool was latency-gapped (2 waves/SIMD both stalled on vmcnt(0)
// with nothing left to issue), not mechanism-limited; 32 waves/CU keeps
// ~256 KiB/CU in flight >> the ~4 KiB needed to cover 900-cyc HBM latency
// at the CU's 10.25 B/cyc HBM share.
__global__ void __launch_bounds__(256, 8)
pool_diff_kernel(const float* __restrict__ orig,
                 const float* __restrict__ enh,
                 float* __restrict__ g, int total) {
    const int idx = blockIdx.x * blockDim.x + threadIdx.x;
    if (idx >= total) return;
    const int j = idx & (PW - 1);
    const int i = (idx >> 7) & (PH - 1);
    const int b = idx >> 14;

    const size_t img  = (size_t)HH * WW;          // 262144
    const size_t base = (size_t)b * CC * img + (size_t)(i * 4) * WW + (size_t)(j * 4);

    f32x4 acc = {0.0f, 0.0f, 0.0f, 0.0f};
#pragma unroll
    for (int c = 0; c < CC; ++c) {
        const float* po = orig + base + (size_t)c * img;
        const float* pe = enh  + base + (size_t)c * img;
        // 8 nt loads in flight per channel; lanes 0..63 cover 1 KiB
        // contiguous per (c,r) pair -> fully coalesced.
        f32x4 o0 = __builtin_nontemporal_load((const f32x4*)(po));
        f32x4 o1 = __builtin_nontemporal_load((const f32x4*)(po + WW));
        f32x4 o2 = __builtin_nontemporal_load((const f32x4*)(po + 2 * WW));
        f32x4 o3 = __builtin_nontemporal_load((const f32x4*)(po + 3 * WW));
        f32x4 e0 = __builtin_nontemporal_load((const f32x4*)(pe));
        f32x4 e1 = __builtin_nontemporal_load((const f32x4*)(pe + WW));
        f32x4 e2 = __builtin_nontemporal_load((const f32x4*)(pe + 2 * WW));
        f32x4 e3 = __builtin_nontemporal_load((const f32x4*)(pe + 3 * WW));
        acc += (o0 - e0);
        acc += (o1 - e1);
        acc += (o2 - e2);
        acc += (o3 - e3);
    }
    const float s = (acc.x + acc.y) + (acc.z + acc.w);
    // Normal (caching) store: stencil_loss_kernel re-reads g, keep it in L2.
    g[idx] = s * (1.0f / 48.0f);
}

// Kernel 2: loss[i,j] = sum over {l,r,u,d} of (g[i,j] - g_pad[neighbor])^2
// Zero padding: out-of-bounds neighbor contributes 0 (so diff = g[i,j]).
__global__ void __launch_bounds__(256)
stencil_loss_kernel(const float* __restrict__ g,
                    float* __restrict__ out, int total) {
    int idx = blockIdx.x * blockDim.x + threadIdx.x;
    if (idx >= total) return;
    int j = idx & (PW - 1);
    int i = (idx >> 7) & (PH - 1);

    float c = g[idx];
    float l = (j > 0)      ? g[idx - 1]  : 0.0f;
    float r = (j < PW - 1) ? g[idx + 1]  : 0.0f;
    float u = (i > 0)      ? g[idx - PW] : 0.0f;
    float d = (i < PH - 1) ? g[idx + PW] : 0.0f;

    float dl = c - l, dr = c - r, du = c - u, dd = c - d;
    __builtin_nontemporal_store(dl * dl + dr * dr + du * du + dd * dd, out + idx);
}

extern "C" void kernel_launch(void* const* d_in, const int* in_sizes, int n_in,
                              void* d_out, int out_size, void* d_ws, size_t ws_size,
                              hipStream_t stream) {
    const float* orig = (const float*)d_in[0];
    const float* enh  = (const float*)d_in[1];
    float* out = (float*)d_out;
    float* g   = (float*)d_ws;  // 32*128*128 floats = 2 MB scratch

    const int batch = in_sizes[0] / (CC * HH * WW);   // 32
    const int total = batch * PH * PW;                // 524288

    const int block = 256;
    const int grid = (total + block - 1) / block;     // 2048

    // Flat full-occupancy grid: 8 blocks/CU resident at VGPR<=64.
    pool_diff_kernel<<<grid, block, 0, stream>>>(orig, enh, g, total);
    stencil_loss_kernel<<<grid, block, 0, stream>>>(g, out, total);
}